// Round 4
// baseline (165.792 us; speedup 1.0000x reference)
//
#include <hip/hip_runtime.h>
#include <math.h>

// Shapes (compile-time)
#define BB 16
#define LL 28
#define RR 64
#define DD 512
#define KK (RR * DD)        // 32768
#define NCHUNK 512          // k-chunks: (r, 64-wide d range)
#define NROLE  1024         // role blocks = NCHUNK x 2 e-halves
#define NEVT   256          // evt blocks: (b, 32-wide d-chunk)

// ---------------------------------------------------------------------------
// Kernel A (fused, no atomics):
//  blocks [0, NROLE): role split-K. Block = (chunk c, e-half h).
//    Prefetch first 8 WRT float4s -> phase 1 builds G slice (64 d x 16 b) in
//    4 KB LDS -> phase 2 streams 65 KB of WRT (8-deep register pipeline,
//    128 B/lane in flight), G via uniform ds_read_b128 broadcast.
//    4 k-streams combined via 2 LDS rounds; partial [16][64]f4 to workspace.
//  blocks [NROLE, NROLE+NEVT): evt transform, batched float4 WTT loads,
//    2-stream LDS combine, partial [128]f4 to workspace.
// ---------------------------------------------------------------------------
__global__ void __launch_bounds__(256) kernel_a(
    const float* __restrict__ logits,   // [B,L,R]
    const float* __restrict__ arg,      // [B,L,D]
    const float* __restrict__ WRT,      // [R,D,D]
    const float* __restrict__ WTT,      // [E,D,D]
    const float* __restrict__ evt_emb,  // [B,1,D]
    const int*   __restrict__ evt_type, // [B]
    float* __restrict__ part,           // [NCHUNK][16][128] float4-granular
    float* __restrict__ evt_part)       // [B*16][128] float4-granular
{
    __shared__ float smem[8192];        // 32 KB
    const int t = threadIdx.x;

    if (blockIdx.x >= NROLE) {
        // ---------------- evt transform ----------------
        const int blk = blockIdx.x - NROLE;
        const int b  = blk >> 4;
        const int dc = blk & 15;
        const int d0 = dc * 32;
        const int ty = evt_type[b];
        const float* Wt = WTT + (size_t)ty * DD * DD;
        const int e4 = t & 127;
        const int s  = t >> 7;          // 2 d-streams
        float4 a = {0.f, 0.f, 0.f, 0.f};
#pragma unroll
        for (int db = 0; db < 32; db += 16) {
            float  em[8];
            float4 w[8];
#pragma unroll
            for (int i = 0; i < 8; ++i) {
                const int d = d0 + db + s + 2 * i;
                em[i] = evt_emb[b * DD + d];                       // uniform
                w[i]  = ((const float4*)(Wt + (size_t)d * DD))[e4];
            }
#pragma unroll
            for (int i = 0; i < 8; ++i) {
                a.x = fmaf(em[i], w[i].x, a.x);
                a.y = fmaf(em[i], w[i].y, a.y);
                a.z = fmaf(em[i], w[i].z, a.z);
                a.w = fmaf(em[i], w[i].w, a.w);
            }
        }
        // combine 2 streams via LDS, plain store (no atomics)
        float4* sm4 = (float4*)smem;
        if (s == 1) sm4[e4] = a;
        __syncthreads();
        if (s == 0) {
            const float4 q = sm4[e4];
            a.x += q.x; a.y += q.y; a.z += q.z; a.w += q.w;
            ((float4*)evt_part)[(size_t)blk * 128 + e4] = a;
        }
        return;
    }

    // ---------------- role split-K ----------------
    const int blk = blockIdx.x;
    const int c  = blk >> 1;            // chunk [0,512)
    const int h  = blk & 1;             // e-half
    const int r  = c >> 3;
    const int d0 = (c & 7) * 64;

    const int e4 = t & 63;              // float4 column within e-half
    const int ks = t >> 6;              // 4 k-streams
    const float4* Wp = (const float4*)(WRT + ((size_t)(r * DD + d0)) * DD + h * 256);

    // Prefetch first WRT batch BEFORE phase 1 so the HBM stream starts now.
    float4 w[8];
#pragma unroll
    for (int i = 0; i < 8; ++i)
        w[i] = Wp[(size_t)(ks + 4 * i) * 128 + e4];

    // Phase 1: G_lds[dd][b], dd in [0,64), b in [0,16). Layout [64][16] floats.
    {
        const int d4 = t & 15;          // float4 d-group (coalesced arg)
        const int b  = t >> 4;
        const float4* ap = (const float4*)(arg + d0) + d4;
        float4 g = {0.f, 0.f, 0.f, 0.f};
#pragma unroll
        for (int l = 0; l < LL; ++l) {
            const float lg = logits[(b * LL + l) * RR + r];
            const float4 av = ap[(size_t)(b * LL + l) * 128];
            g.x = fmaf(lg, av.x, g.x);
            g.y = fmaf(lg, av.y, g.y);
            g.z = fmaf(lg, av.z, g.z);
            g.w = fmaf(lg, av.w, g.w);
        }
        smem[(4 * d4 + 0) * 16 + b] = g.x;
        smem[(4 * d4 + 1) * 16 + b] = g.y;
        smem[(4 * d4 + 2) * 16 + b] = g.z;
        smem[(4 * d4 + 3) * 16 + b] = g.w;
    }
    __syncthreads();

    // Phase 2: software-pipelined K-loop, 8 float4 loads in flight per lane.
    const float4* Gl = (const float4*)smem;   // [64][4] float4
    float4 acc[16];
#pragma unroll
    for (int b = 0; b < 16; ++b) acc[b] = make_float4(0.f, 0.f, 0.f, 0.f);

#pragma unroll
    for (int kb = 0; kb < 2; ++kb) {
        float4 wn[8];
        if (kb == 0) {
#pragma unroll
            for (int i = 0; i < 8; ++i)
                wn[i] = Wp[(size_t)(ks + 4 * (8 + i)) * 128 + e4];
        }
#pragma unroll
        for (int i = 0; i < 8; ++i) {
            const int kk = ks + 4 * (kb * 8 + i);
            float4 g[4];
            g[0] = Gl[kk * 4 + 0];      // uniform broadcast reads
            g[1] = Gl[kk * 4 + 1];
            g[2] = Gl[kk * 4 + 2];
            g[3] = Gl[kk * 4 + 3];
            const float* gs = (const float*)g;
#pragma unroll
            for (int b = 0; b < 16; ++b) {
                acc[b].x = fmaf(gs[b], w[i].x, acc[b].x);
                acc[b].y = fmaf(gs[b], w[i].y, acc[b].y);
                acc[b].z = fmaf(gs[b], w[i].z, acc[b].z);
                acc[b].w = fmaf(gs[b], w[i].w, acc[b].w);
            }
        }
#pragma unroll
        for (int i = 0; i < 8; ++i) w[i] = wn[i];
    }
    __syncthreads();   // G region no longer needed

    // Combine 4 k-streams: round A (streams 2,3 -> 0,1), round B (1 -> 0).
    float4* sm4 = (float4*)smem;
    if (ks >= 2) {
#pragma unroll
        for (int b = 0; b < 16; ++b) sm4[(ks - 2) * 1024 + e4 * 16 + b] = acc[b];
    }
    __syncthreads();
    if (ks < 2) {
#pragma unroll
        for (int b = 0; b < 16; ++b) {
            const float4 q = sm4[ks * 1024 + e4 * 16 + b];
            acc[b].x += q.x; acc[b].y += q.y; acc[b].z += q.z; acc[b].w += q.w;
        }
    }
    __syncthreads();
    if (ks == 1) {
#pragma unroll
        for (int b = 0; b < 16; ++b) sm4[e4 * 16 + b] = acc[b];
    }
    __syncthreads();
    if (ks == 0) {
        float4* po = (float4*)part + (size_t)c * 2048;   // [16][128] float4
#pragma unroll
        for (int b = 0; b < 16; ++b) {
            float4 o = acc[b];
            const float4 q = sm4[e4 * 16 + b];
            o.x += q.x; o.y += q.y; o.z += q.z; o.w += q.w;
            po[b * 128 + h * 64 + e4] = o;
        }
    }
}

// ---------------------------------------------------------------------------
// Reduce (no atomics, plain stores — also removes the need for memset):
//  blocks [0,128): div_acc[o4] = sum_{p<512} part[p][o4]; block owns 16 f4
//    outputs x 16 p-groups of 32; LDS combine.
//  blocks [128,136): evt_acc[o4] = sum_{dc<16} evt_part[b*16+dc][e4].
// ---------------------------------------------------------------------------
__global__ void __launch_bounds__(256) kernel_reduce(
    const float* __restrict__ part,     // [512][2048] float4-granular
    const float* __restrict__ evt_part, // [256][128] float4-granular
    float* __restrict__ div_acc,        // [8192]
    float* __restrict__ evt_acc)        // [8192]
{
    const int t = threadIdx.x;
    if (blockIdx.x < 128) {
        __shared__ float4 sred[256];
        const int oo = t & 15;
        const int pg = t >> 4;
        const int o4 = blockIdx.x * 16 + oo;
        const float4* p4 = (const float4*)part;
        float4 s = {0.f, 0.f, 0.f, 0.f};
#pragma unroll 8
        for (int i = 0; i < 32; ++i) {
            const int p = pg * 32 + i;
            const float4 v = p4[(size_t)p * 2048 + o4];
            s.x += v.x; s.y += v.y; s.z += v.z; s.w += v.w;
        }
        sred[pg * 16 + oo] = s;
        __syncthreads();
        if (t < 16) {
            float4 tot = sred[t];
#pragma unroll
            for (int g = 1; g < 16; ++g) {
                const float4 v = sred[g * 16 + t];
                tot.x += v.x; tot.y += v.y; tot.z += v.z; tot.w += v.w;
            }
            ((float4*)div_acc)[blockIdx.x * 16 + t] = tot;
        }
    } else {
        const int o4 = (blockIdx.x - 128) * 256 + t;   // [0,2048)
        const int b  = o4 >> 7;
        const int el = o4 & 127;
        const float4* e4p = (const float4*)evt_part;
        float4 s = {0.f, 0.f, 0.f, 0.f};
#pragma unroll
        for (int dc = 0; dc < 16; ++dc) {
            const float4 v = e4p[(size_t)(b * 16 + dc) * 128 + el];
            s.x += v.x; s.y += v.y; s.z += v.z; s.w += v.w;
        }
        ((float4*)evt_acc)[o4] = s;
    }
}

// ---------------------------------------------------------------------------
// MLP: graph=(div+evt)/2 ; h=relu(graph@w1+b1) ; out=sigmoid(h@w2+b2)
// ---------------------------------------------------------------------------
__global__ void __launch_bounds__(256) kernel_mlp(
    const float* __restrict__ div_acc,  // [B,D]
    const float* __restrict__ evt_acc,  // [B,D]
    const float* __restrict__ w1,       // [D,64]
    const float* __restrict__ b1,       // [64]
    const float* __restrict__ w2,       // [64,1]
    const float* __restrict__ b2,       // [1]
    float* __restrict__ out)            // [B,1]
{
    __shared__ float hred[256];
    const int b  = blockIdx.x;
    const int t  = threadIdx.x;
    const int j  = t & 63;
    const int dq = t >> 6;
    float hp = 0.f;
#pragma unroll 8
    for (int i = 0; i < 128; ++i) {
        const int d = dq * 128 + i;
        const float g = (div_acc[b * DD + d] + evt_acc[b * DD + d]) * 0.5f;
        hp = fmaf(g, w1[d * 64 + j], hp);
    }
    hred[t] = hp;
    __syncthreads();
    if (t < 64) {
        float h = b1[j] + hred[j] + hred[64 + j] + hred[128 + j] + hred[192 + j];
        h = fmaxf(h, 0.f);
        float v = h * w2[j];
#pragma unroll
        for (int off = 32; off > 0; off >>= 1) v += __shfl_down(v, off, 64);
        if (j == 0) out[b] = 1.f / (1.f + expf(-(v + b2[0])));
    }
}

// ---------------------------------------------------------------------------
extern "C" void kernel_launch(void* const* d_in, const int* in_sizes, int n_in,
                              void* d_out, int out_size, void* d_ws, size_t ws_size,
                              hipStream_t stream) {
    const float* logits   = (const float*)d_in[0];
    const float* evt_emb  = (const float*)d_in[1];
    const float* arg_emb  = (const float*)d_in[2];
    // d_in[3] arg_padding_num cancels algebraically; unused
    const int*   evt_type = (const int*)d_in[4];
    const float* WRT      = (const float*)d_in[5];
    const float* WTT      = (const float*)d_in[6];
    const float* w1       = (const float*)d_in[7];
    const float* b1       = (const float*)d_in[8];
    const float* w2       = (const float*)d_in[9];
    const float* b2       = (const float*)d_in[10];
    float* out = (float*)d_out;

    float* part     = (float*)d_ws;                      // 512*8192 floats = 16.78 MB
    float* evt_part = part + (size_t)NCHUNK * 8192;      // 256*512 floats = 512 KB
    float* div_acc  = evt_part + NEVT * DD;              // 8192 floats
    float* evt_acc  = div_acc + BB * DD;                 // 8192 floats

    hipLaunchKernelGGL(kernel_a, dim3(NROLE + NEVT), dim3(256), 0, stream,
                       logits, arg_emb, WRT, WTT, evt_emb, evt_type, part, evt_part);
    hipLaunchKernelGGL(kernel_reduce, dim3(136), dim3(256), 0, stream,
                       part, evt_part, div_acc, evt_acc);
    hipLaunchKernelGGL(kernel_mlp, dim3(BB), dim3(256), 0, stream,
                       div_acc, evt_acc, w1, b1, w2, b2, out);
}

// Round 5
// 160.600 us; speedup vs baseline: 1.0323x; 1.0323x over previous
//
#include <hip/hip_runtime.h>
#include <math.h>

// Shapes (compile-time)
#define BB 16
#define LL 28
#define RR 64
#define DD 512
#define KK (RR * DD)        // 32768
#define NROLE 256           // role chunks: (r-pair, 64-wide d range) -> k=128 each
#define NEVT  256           // evt chunks: (b, 32-wide d range)

// ---------------------------------------------------------------------------
// Kernel A (fused, no atomics, no inter-wave combine):
//  even blockIdx -> role chunk cid: phase 1 builds G[128 rows][16 b] in 8 KB
//    LDS (arg float4 reused across the r-pair), ONE barrier; phase 2 streams
//    256 KB of WRT (8-deep register double-buffered float4 pipeline), G via
//    uniform ds_read_b128 broadcasts. Waves own DISJOINT b-halves -> partial
//    rows stored directly to part[cid][16][512] (8.4 MB total), no combine.
//  odd blockIdx -> evt chunk: batched float4 WTT loads, 2-stream LDS combine
//    (conflict-free consecutive-f4 layout), partial to evt_part.
// ---------------------------------------------------------------------------
__global__ void __launch_bounds__(256) kernel_a(
    const float* __restrict__ logits,   // [B,L,R]
    const float* __restrict__ arg,      // [B,L,D]
    const float* __restrict__ WRT,      // [R,D,D]
    const float* __restrict__ WTT,      // [E,D,D]
    const float* __restrict__ evt_emb,  // [B,1,D]
    const int*   __restrict__ evt_type, // [B]
    float* __restrict__ part,           // [NROLE][16][128] float4-granular
    float* __restrict__ evt_part)       // [B*16][128] float4-granular
{
    __shared__ float smem[2048];        // 8 KB
    const int t   = threadIdx.x;
    const int cid = blockIdx.x >> 1;

    if (blockIdx.x & 1) {
        // ---------------- evt transform ----------------
        const int b  = cid >> 4;
        const int dc = cid & 15;
        const int d0 = dc * 32;
        const int ty = evt_type[b];
        const float* Wt = WTT + (size_t)ty * DD * DD;
        const int e4 = t & 127;
        const int s  = t >> 7;          // 2 d-streams
        float4 a = {0.f, 0.f, 0.f, 0.f};
#pragma unroll
        for (int db = 0; db < 32; db += 16) {
            float  em[8];
            float4 w[8];
#pragma unroll
            for (int i = 0; i < 8; ++i) {
                const int d = d0 + db + s + 2 * i;
                em[i] = evt_emb[b * DD + d];                       // uniform
                w[i]  = ((const float4*)(Wt + (size_t)d * DD))[e4];
            }
#pragma unroll
            for (int i = 0; i < 8; ++i) {
                a.x = fmaf(em[i], w[i].x, a.x);
                a.y = fmaf(em[i], w[i].y, a.y);
                a.z = fmaf(em[i], w[i].z, a.z);
                a.w = fmaf(em[i], w[i].w, a.w);
            }
        }
        // combine 2 streams via LDS (consecutive-f4 layout: conflict-free)
        float4* sm4 = (float4*)smem;
        if (s == 1) sm4[e4] = a;
        __syncthreads();
        if (s == 0) {
            const float4 q = sm4[e4];
            a.x += q.x; a.y += q.y; a.z += q.z; a.w += q.w;
            ((float4*)evt_part)[(size_t)cid * 128 + e4] = a;
        }
        return;
    }

    // ---------------- role chunk: (r-pair rp, d-range d0) ----------------
    const int rp = cid >> 3;            // [0,32)
    const int r0 = rp * 2;
    const int d0 = (cid & 7) * 64;

    const float4* W0 = (const float4*)(WRT + ((size_t)r0       * DD + d0) * DD);
    const float4* W1 = (const float4*)(WRT + ((size_t)(r0 + 1) * DD + d0) * DD);

    const int e4 = t & 127;             // float4 e-column
    const int bh = t >> 7;              // b-half (waves own disjoint b rows)

    // Prefetch WRT batch 0 (rows 0..7 of W0) BEFORE phase 1.
    float4 w[8];
#pragma unroll
    for (int i = 0; i < 8; ++i)
        w[i] = W0[(size_t)i * 128 + e4];

    // Phase 1: G[row][b], row = rl*64 + d-local in [0,128), b in [0,16).
    {
        const int b  = t >> 4;
        const int d4 = t & 15;          // float4 d-group (coalesced arg)
        const float4* ap = (const float4*)(arg) + (size_t)(b * LL) * 128 + (d0 >> 2) + d4;
        const float*  lp = logits + (b * LL) * RR + r0;
        float4 g0 = {0.f, 0.f, 0.f, 0.f};
        float4 g1 = {0.f, 0.f, 0.f, 0.f};
#pragma unroll 7
        for (int l = 0; l < LL; ++l) {
            const float4 av = ap[(size_t)l * 128];
            const float l0 = lp[l * RR];
            const float l1 = lp[l * RR + 1];
            g0.x = fmaf(l0, av.x, g0.x); g0.y = fmaf(l0, av.y, g0.y);
            g0.z = fmaf(l0, av.z, g0.z); g0.w = fmaf(l0, av.w, g0.w);
            g1.x = fmaf(l1, av.x, g1.x); g1.y = fmaf(l1, av.y, g1.y);
            g1.z = fmaf(l1, av.z, g1.z); g1.w = fmaf(l1, av.w, g1.w);
        }
        smem[(4 * d4 + 0) * 16 + b]        = g0.x;
        smem[(4 * d4 + 1) * 16 + b]        = g0.y;
        smem[(4 * d4 + 2) * 16 + b]        = g0.z;
        smem[(4 * d4 + 3) * 16 + b]        = g0.w;
        smem[(64 + 4 * d4 + 0) * 16 + b]   = g1.x;
        smem[(64 + 4 * d4 + 1) * 16 + b]   = g1.y;
        smem[(64 + 4 * d4 + 2) * 16 + b]   = g1.z;
        smem[(64 + 4 * d4 + 3) * 16 + b]   = g1.w;
    }
    __syncthreads();                    // the ONLY barrier in the role path

    // Phase 2: 16 batches of 8 k-rows, register double-buffered.
    float4 acc[8];
#pragma unroll
    for (int i = 0; i < 8; ++i) acc[i] = make_float4(0.f, 0.f, 0.f, 0.f);

    const float* G = smem;              // [128][16]
    for (int kb = 0; kb < 16; ++kb) {
        // prefetch next batch (wraps harmlessly on the last iteration)
        const int kbn = (kb + 1) & 15;
        const float4* Wn = (kbn < 8) ? W0 : W1;
        const int rbase = (kbn & 7) * 8;
        float4 wn[8];
#pragma unroll
        for (int i = 0; i < 8; ++i)
            wn[i] = Wn[(size_t)(rbase + i) * 128 + e4];
#pragma unroll
        for (int i = 0; i < 8; ++i) {
            const int kk = kb * 8 + i;
            // this wave's 8 b-values: uniform b128 broadcasts (no conflicts)
            const float4 ga = ((const float4*)(G + kk * 16 + 8 * bh))[0];
            const float4 gb = ((const float4*)(G + kk * 16 + 8 * bh))[1];
            acc[0].x = fmaf(ga.x, w[i].x, acc[0].x); acc[0].y = fmaf(ga.x, w[i].y, acc[0].y);
            acc[0].z = fmaf(ga.x, w[i].z, acc[0].z); acc[0].w = fmaf(ga.x, w[i].w, acc[0].w);
            acc[1].x = fmaf(ga.y, w[i].x, acc[1].x); acc[1].y = fmaf(ga.y, w[i].y, acc[1].y);
            acc[1].z = fmaf(ga.y, w[i].z, acc[1].z); acc[1].w = fmaf(ga.y, w[i].w, acc[1].w);
            acc[2].x = fmaf(ga.z, w[i].x, acc[2].x); acc[2].y = fmaf(ga.z, w[i].y, acc[2].y);
            acc[2].z = fmaf(ga.z, w[i].z, acc[2].z); acc[2].w = fmaf(ga.z, w[i].w, acc[2].w);
            acc[3].x = fmaf(ga.w, w[i].x, acc[3].x); acc[3].y = fmaf(ga.w, w[i].y, acc[3].y);
            acc[3].z = fmaf(ga.w, w[i].z, acc[3].z); acc[3].w = fmaf(ga.w, w[i].w, acc[3].w);
            acc[4].x = fmaf(gb.x, w[i].x, acc[4].x); acc[4].y = fmaf(gb.x, w[i].y, acc[4].y);
            acc[4].z = fmaf(gb.x, w[i].z, acc[4].z); acc[4].w = fmaf(gb.x, w[i].w, acc[4].w);
            acc[5].x = fmaf(gb.y, w[i].x, acc[5].x); acc[5].y = fmaf(gb.y, w[i].y, acc[5].y);
            acc[5].z = fmaf(gb.y, w[i].z, acc[5].z); acc[5].w = fmaf(gb.y, w[i].w, acc[5].w);
            acc[6].x = fmaf(gb.z, w[i].x, acc[6].x); acc[6].y = fmaf(gb.z, w[i].y, acc[6].y);
            acc[6].z = fmaf(gb.z, w[i].z, acc[6].z); acc[6].w = fmaf(gb.z, w[i].w, acc[6].w);
            acc[7].x = fmaf(gb.w, w[i].x, acc[7].x); acc[7].y = fmaf(gb.w, w[i].y, acc[7].y);
            acc[7].z = fmaf(gb.w, w[i].z, acc[7].z); acc[7].w = fmaf(gb.w, w[i].w, acc[7].w);
        }
#pragma unroll
        for (int i = 0; i < 8; ++i) w[i] = wn[i];
    }

    // Store this wave's disjoint partial rows (coalesced, fire-and-forget).
    float4* po = (float4*)part + (size_t)cid * 2048;   // [16][128] float4
#pragma unroll
    for (int i = 0; i < 8; ++i)
        po[(8 * bh + i) * 128 + e4] = acc[i];
}

// ---------------------------------------------------------------------------
// Reduce (plain stores):
//  blocks [0,64): div_acc — block owns 32 f4 outputs; 8 p-groups of 32 chunks;
//    LDS combine.
//  blocks [64,72): evt_acc — sum 16 d-chunks per (b, e4).
// ---------------------------------------------------------------------------
__global__ void __launch_bounds__(256) kernel_reduce(
    const float* __restrict__ part,     // [NROLE][2048] float4-granular
    const float* __restrict__ evt_part, // [256][128] float4-granular
    float* __restrict__ div_acc,        // [8192]
    float* __restrict__ evt_acc)        // [8192]
{
    const int t = threadIdx.x;
    if (blockIdx.x < 64) {
        __shared__ float4 sred[256];
        const int oo = t & 31;
        const int pg = t >> 5;          // 8 groups x 32 chunks
        const int o4 = blockIdx.x * 32 + oo;
        const float4* p4 = (const float4*)part;
        float4 s = {0.f, 0.f, 0.f, 0.f};
#pragma unroll 8
        for (int i = 0; i < 32; ++i) {
            const int p = pg * 32 + i;
            const float4 v = p4[(size_t)p * 2048 + o4];
            s.x += v.x; s.y += v.y; s.z += v.z; s.w += v.w;
        }
        sred[pg * 32 + oo] = s;
        __syncthreads();
        if (t < 32) {
            float4 tot = sred[t];
#pragma unroll
            for (int g = 1; g < 8; ++g) {
                const float4 v = sred[g * 32 + t];
                tot.x += v.x; tot.y += v.y; tot.z += v.z; tot.w += v.w;
            }
            ((float4*)div_acc)[blockIdx.x * 32 + t] = tot;
        }
    } else {
        const int o4 = (blockIdx.x - 64) * 256 + t;    // [0,2048)
        const int b  = o4 >> 7;
        const int el = o4 & 127;
        const float4* e4p = (const float4*)evt_part;
        float4 s = {0.f, 0.f, 0.f, 0.f};
#pragma unroll
        for (int dc = 0; dc < 16; ++dc) {
            const float4 v = e4p[(size_t)(b * 16 + dc) * 128 + el];
            s.x += v.x; s.y += v.y; s.z += v.z; s.w += v.w;
        }
        ((float4*)evt_acc)[o4] = s;
    }
}

// ---------------------------------------------------------------------------
// MLP: graph=(div+evt)/2 ; h=relu(graph@w1+b1) ; out=sigmoid(h@w2+b2)
// ---------------------------------------------------------------------------
__global__ void __launch_bounds__(256) kernel_mlp(
    const float* __restrict__ div_acc,  // [B,D]
    const float* __restrict__ evt_acc,  // [B,D]
    const float* __restrict__ w1,       // [D,64]
    const float* __restrict__ b1,       // [64]
    const float* __restrict__ w2,       // [64,1]
    const float* __restrict__ b2,       // [1]
    float* __restrict__ out)            // [B,1]
{
    __shared__ float hred[256];
    const int b  = blockIdx.x;
    const int t  = threadIdx.x;
    const int j  = t & 63;
    const int dq = t >> 6;
    float hp = 0.f;
#pragma unroll 8
    for (int i = 0; i < 128; ++i) {
        const int d = dq * 128 + i;
        const float g = (div_acc[b * DD + d] + evt_acc[b * DD + d]) * 0.5f;
        hp = fmaf(g, w1[d * 64 + j], hp);
    }
    hred[t] = hp;
    __syncthreads();
    if (t < 64) {
        float h = b1[j] + hred[j] + hred[64 + j] + hred[128 + j] + hred[192 + j];
        h = fmaxf(h, 0.f);
        float v = h * w2[j];
#pragma unroll
        for (int off = 32; off > 0; off >>= 1) v += __shfl_down(v, off, 64);
        if (j == 0) out[b] = 1.f / (1.f + expf(-(v + b2[0])));
    }
}

// ---------------------------------------------------------------------------
extern "C" void kernel_launch(void* const* d_in, const int* in_sizes, int n_in,
                              void* d_out, int out_size, void* d_ws, size_t ws_size,
                              hipStream_t stream) {
    const float* logits   = (const float*)d_in[0];
    const float* evt_emb  = (const float*)d_in[1];
    const float* arg_emb  = (const float*)d_in[2];
    // d_in[3] arg_padding_num cancels algebraically; unused
    const int*   evt_type = (const int*)d_in[4];
    const float* WRT      = (const float*)d_in[5];
    const float* WTT      = (const float*)d_in[6];
    const float* w1       = (const float*)d_in[7];
    const float* b1       = (const float*)d_in[8];
    const float* w2       = (const float*)d_in[9];
    const float* b2       = (const float*)d_in[10];
    float* out = (float*)d_out;

    float* part     = (float*)d_ws;                      // 256*8192 floats = 8.39 MB
    float* evt_part = part + (size_t)NROLE * 8192;       // 256*512 floats = 512 KB
    float* div_acc  = evt_part + NEVT * DD;              // 8192 floats
    float* evt_acc  = div_acc + BB * DD;                 // 8192 floats

    hipLaunchKernelGGL(kernel_a, dim3(NROLE + NEVT), dim3(256), 0, stream,
                       logits, arg_emb, WRT, WTT, evt_emb, evt_type, part, evt_part);
    hipLaunchKernelGGL(kernel_reduce, dim3(72), dim3(256), 0, stream,
                       part, evt_part, div_acc, evt_acc);
    hipLaunchKernelGGL(kernel_mlp, dim3(BB), dim3(256), 0, stream,
                       div_acc, evt_acc, w1, b1, w2, b2, out);
}

// Round 6
// 156.489 us; speedup vs baseline: 1.0594x; 1.0263x over previous
//
#include <hip/hip_runtime.h>
#include <math.h>

// Shapes (compile-time)
#define BB 16
#define LL 28
#define RR 64
#define DD 512
#define NROLE 512           // role chunks: (r, 64-wide d range) -> k=64 each
#define NEVT  256           // evt chunks: (b, 32-wide d range)

// ---------------------------------------------------------------------------
// Kernel A (fused, no atomics, no inter-wave combine, 3 blocks/CU):
//  blockIdx%3 in {0,1} -> role chunk rid=2*(blockIdx/3)+rem:
//    phase 1 builds G[64 rows][16 b] in 4 KB LDS (float4 arg loads), ONE
//    barrier; phase 2 streams 128 KB of WRT (8-deep register float4
//    pipeline), G via uniform ds_read_b128 broadcasts. Waves own DISJOINT
//    b-halves -> partial rows stored directly to part[rid][16][512].
//  blockIdx%3==2 -> evt chunk cid=blockIdx/3: batched float4 WTT loads,
//    2-stream LDS combine, partial to evt_part.
// ---------------------------------------------------------------------------
__global__ void __launch_bounds__(256, 3) kernel_a(
    const float* __restrict__ logits,   // [B,L,R]
    const float* __restrict__ arg,      // [B,L,D]
    const float* __restrict__ WRT,      // [R,D,D]
    const float* __restrict__ WTT,      // [E,D,D]
    const float* __restrict__ evt_emb,  // [B,1,D]
    const int*   __restrict__ evt_type, // [B]
    float* __restrict__ part,           // [NROLE][16][128] float4-granular
    float* __restrict__ evt_part)       // [B*16][128] float4-granular
{
    __shared__ float smem[1024];        // 4 KB
    const int t   = threadIdx.x;
    const int q   = blockIdx.x / 3;
    const int rem = blockIdx.x - 3 * q;

    if (rem == 2) {
        // ---------------- evt transform ----------------
        const int cid = q;              // [0,256)
        const int b  = cid >> 4;
        const int dc = cid & 15;
        const int d0 = dc * 32;
        const int ty = evt_type[b];
        const float* Wt = WTT + (size_t)ty * DD * DD;
        const int e4 = t & 127;
        const int s  = t >> 7;          // 2 d-streams
        float4 a = {0.f, 0.f, 0.f, 0.f};
#pragma unroll
        for (int db = 0; db < 32; db += 16) {
            float  em[8];
            float4 w[8];
#pragma unroll
            for (int i = 0; i < 8; ++i) {
                const int d = d0 + db + s + 2 * i;
                em[i] = evt_emb[b * DD + d];                       // uniform
                w[i]  = ((const float4*)(Wt + (size_t)d * DD))[e4];
            }
#pragma unroll
            for (int i = 0; i < 8; ++i) {
                a.x = fmaf(em[i], w[i].x, a.x);
                a.y = fmaf(em[i], w[i].y, a.y);
                a.z = fmaf(em[i], w[i].z, a.z);
                a.w = fmaf(em[i], w[i].w, a.w);
            }
        }
        // combine 2 streams via LDS (consecutive-f4 layout: conflict-free)
        float4* sm4 = (float4*)smem;
        if (s == 1) sm4[e4] = a;
        __syncthreads();
        if (s == 0) {
            const float4 q4 = sm4[e4];
            a.x += q4.x; a.y += q4.y; a.z += q4.z; a.w += q4.w;
            ((float4*)evt_part)[(size_t)cid * 128 + e4] = a;
        }
        return;
    }

    // ---------------- role chunk: (r, d-range d0), k = 64 ----------------
    const int rid = 2 * q + rem;        // [0,512)
    const int r  = rid >> 3;
    const int d0 = (rid & 7) * 64;

    const float4* Wp = (const float4*)(WRT + ((size_t)r * DD + d0) * DD);

    const int e4 = t & 127;             // float4 e-column
    const int bh = t >> 7;              // b-half (waves own disjoint b rows)

    // Prefetch WRT batch 0 (k-rows 0..7) BEFORE phase 1.
    float4 w[8];
#pragma unroll
    for (int i = 0; i < 8; ++i)
        w[i] = Wp[(size_t)i * 128 + e4];

    // Phase 1: G[row][b], row = d-local in [0,64), b in [0,16).
    {
        const int b  = t >> 4;
        const int d4 = t & 15;          // float4 d-group (coalesced arg)
        const float4* ap = (const float4*)(arg) + (size_t)(b * LL) * 128 + (d0 >> 2) + d4;
        const float*  lp = logits + (b * LL) * RR + r;
        float4 g = {0.f, 0.f, 0.f, 0.f};
#pragma unroll 7
        for (int l = 0; l < LL; ++l) {
            const float4 av = ap[(size_t)l * 128];
            const float lg = lp[l * RR];
            g.x = fmaf(lg, av.x, g.x);
            g.y = fmaf(lg, av.y, g.y);
            g.z = fmaf(lg, av.z, g.z);
            g.w = fmaf(lg, av.w, g.w);
        }
        smem[(4 * d4 + 0) * 16 + b] = g.x;
        smem[(4 * d4 + 1) * 16 + b] = g.y;
        smem[(4 * d4 + 2) * 16 + b] = g.z;
        smem[(4 * d4 + 3) * 16 + b] = g.w;
    }
    __syncthreads();                    // the ONLY barrier in the role path

    // Phase 2: 8 batches of 8 k-rows, register double-buffered.
    float4 acc[8];
#pragma unroll
    for (int i = 0; i < 8; ++i) acc[i] = make_float4(0.f, 0.f, 0.f, 0.f);

    const float* G = smem;              // [64][16]
    for (int kb = 0; kb < 8; ++kb) {
        const int kbn = (kb + 1) & 7;   // wraps harmlessly on last iter
        float4 wn[8];
#pragma unroll
        for (int i = 0; i < 8; ++i)
            wn[i] = Wp[(size_t)(kbn * 8 + i) * 128 + e4];
#pragma unroll
        for (int i = 0; i < 8; ++i) {
            const int kk = kb * 8 + i;
            // this wave's 8 b-values: uniform b128 broadcasts (no conflicts)
            const float4 ga = ((const float4*)(G + kk * 16 + 8 * bh))[0];
            const float4 gb = ((const float4*)(G + kk * 16 + 8 * bh))[1];
            acc[0].x = fmaf(ga.x, w[i].x, acc[0].x); acc[0].y = fmaf(ga.x, w[i].y, acc[0].y);
            acc[0].z = fmaf(ga.x, w[i].z, acc[0].z); acc[0].w = fmaf(ga.x, w[i].w, acc[0].w);
            acc[1].x = fmaf(ga.y, w[i].x, acc[1].x); acc[1].y = fmaf(ga.y, w[i].y, acc[1].y);
            acc[1].z = fmaf(ga.y, w[i].z, acc[1].z); acc[1].w = fmaf(ga.y, w[i].w, acc[1].w);
            acc[2].x = fmaf(ga.z, w[i].x, acc[2].x); acc[2].y = fmaf(ga.z, w[i].y, acc[2].y);
            acc[2].z = fmaf(ga.z, w[i].z, acc[2].z); acc[2].w = fmaf(ga.z, w[i].w, acc[2].w);
            acc[3].x = fmaf(ga.w, w[i].x, acc[3].x); acc[3].y = fmaf(ga.w, w[i].y, acc[3].y);
            acc[3].z = fmaf(ga.w, w[i].z, acc[3].z); acc[3].w = fmaf(ga.w, w[i].w, acc[3].w);
            acc[4].x = fmaf(gb.x, w[i].x, acc[4].x); acc[4].y = fmaf(gb.x, w[i].y, acc[4].y);
            acc[4].z = fmaf(gb.x, w[i].z, acc[4].z); acc[4].w = fmaf(gb.x, w[i].w, acc[4].w);
            acc[5].x = fmaf(gb.y, w[i].x, acc[5].x); acc[5].y = fmaf(gb.y, w[i].y, acc[5].y);
            acc[5].z = fmaf(gb.y, w[i].z, acc[5].z); acc[5].w = fmaf(gb.y, w[i].w, acc[5].w);
            acc[6].x = fmaf(gb.z, w[i].x, acc[6].x); acc[6].y = fmaf(gb.z, w[i].y, acc[6].y);
            acc[6].z = fmaf(gb.z, w[i].z, acc[6].z); acc[6].w = fmaf(gb.z, w[i].w, acc[6].w);
            acc[7].x = fmaf(gb.w, w[i].x, acc[7].x); acc[7].y = fmaf(gb.w, w[i].y, acc[7].y);
            acc[7].z = fmaf(gb.w, w[i].z, acc[7].z); acc[7].w = fmaf(gb.w, w[i].w, acc[7].w);
        }
#pragma unroll
        for (int i = 0; i < 8; ++i) w[i] = wn[i];
    }

    // Store this wave's disjoint partial rows (coalesced, fire-and-forget).
    float4* po = (float4*)part + (size_t)rid * 2048;   // [16][128] float4
#pragma unroll
    for (int i = 0; i < 8; ++i)
        po[(8 * bh + i) * 128 + e4] = acc[i];
}

// ---------------------------------------------------------------------------
// Reduce (plain stores):
//  blocks [0,128): div_acc — block owns 16 f4 outputs; 16 p-groups of 32;
//    LDS combine.
//  blocks [128,136): evt_acc — sum 16 d-chunks per (b, e4).
// ---------------------------------------------------------------------------
__global__ void __launch_bounds__(256) kernel_reduce(
    const float* __restrict__ part,     // [NROLE][2048] float4-granular
    const float* __restrict__ evt_part, // [256][128] float4-granular
    float* __restrict__ div_acc,        // [8192]
    float* __restrict__ evt_acc)        // [8192]
{
    const int t = threadIdx.x;
    if (blockIdx.x < 128) {
        __shared__ float4 sred[256];
        const int oo = t & 15;
        const int pg = t >> 4;          // 16 groups x 32 chunks
        const int o4 = blockIdx.x * 16 + oo;
        const float4* p4 = (const float4*)part;
        float4 s = {0.f, 0.f, 0.f, 0.f};
#pragma unroll 8
        for (int i = 0; i < 32; ++i) {
            const int p = pg * 32 + i;
            const float4 v = p4[(size_t)p * 2048 + o4];
            s.x += v.x; s.y += v.y; s.z += v.z; s.w += v.w;
        }
        sred[pg * 16 + oo] = s;
        __syncthreads();
        if (t < 16) {
            float4 tot = sred[t];
#pragma unroll
            for (int g = 1; g < 16; ++g) {
                const float4 v = sred[g * 16 + t];
                tot.x += v.x; tot.y += v.y; tot.z += v.z; tot.w += v.w;
            }
            ((float4*)div_acc)[blockIdx.x * 16 + t] = tot;
        }
    } else {
        const int o4 = (blockIdx.x - 128) * 256 + t;   // [0,2048)
        const int b  = o4 >> 7;
        const int el = o4 & 127;
        const float4* e4p = (const float4*)evt_part;
        float4 s = {0.f, 0.f, 0.f, 0.f};
#pragma unroll
        for (int dc = 0; dc < 16; ++dc) {
            const float4 v = e4p[(size_t)(b * 16 + dc) * 128 + el];
            s.x += v.x; s.y += v.y; s.z += v.z; s.w += v.w;
        }
        ((float4*)evt_acc)[o4] = s;
    }
}

// ---------------------------------------------------------------------------
// MLP: graph=(div+evt)/2 ; h=relu(graph@w1+b1) ; out=sigmoid(h@w2+b2)
// ---------------------------------------------------------------------------
__global__ void __launch_bounds__(256) kernel_mlp(
    const float* __restrict__ div_acc,  // [B,D]
    const float* __restrict__ evt_acc,  // [B,D]
    const float* __restrict__ w1,       // [D,64]
    const float* __restrict__ b1,       // [64]
    const float* __restrict__ w2,       // [64,1]
    const float* __restrict__ b2,       // [1]
    float* __restrict__ out)            // [B,1]
{
    __shared__ float hred[256];
    const int b  = blockIdx.x;
    const int t  = threadIdx.x;
    const int j  = t & 63;
    const int dq = t >> 6;
    float hp = 0.f;
#pragma unroll 8
    for (int i = 0; i < 128; ++i) {
        const int d = dq * 128 + i;
        const float g = (div_acc[b * DD + d] + evt_acc[b * DD + d]) * 0.5f;
        hp = fmaf(g, w1[d * 64 + j], hp);
    }
    hred[t] = hp;
    __syncthreads();
    if (t < 64) {
        float h = b1[j] + hred[j] + hred[64 + j] + hred[128 + j] + hred[192 + j];
        h = fmaxf(h, 0.f);
        float v = h * w2[j];
#pragma unroll
        for (int off = 32; off > 0; off >>= 1) v += __shfl_down(v, off, 64);
        if (j == 0) out[b] = 1.f / (1.f + expf(-(v + b2[0])));
    }
}

// ---------------------------------------------------------------------------
extern "C" void kernel_launch(void* const* d_in, const int* in_sizes, int n_in,
                              void* d_out, int out_size, void* d_ws, size_t ws_size,
                              hipStream_t stream) {
    const float* logits   = (const float*)d_in[0];
    const float* evt_emb  = (const float*)d_in[1];
    const float* arg_emb  = (const float*)d_in[2];
    // d_in[3] arg_padding_num cancels algebraically; unused
    const int*   evt_type = (const int*)d_in[4];
    const float* WRT      = (const float*)d_in[5];
    const float* WTT      = (const float*)d_in[6];
    const float* w1       = (const float*)d_in[7];
    const float* b1       = (const float*)d_in[8];
    const float* w2       = (const float*)d_in[9];
    const float* b2       = (const float*)d_in[10];
    float* out = (float*)d_out;

    float* part     = (float*)d_ws;                      // 512*8192 floats = 16.78 MB
    float* evt_part = part + (size_t)NROLE * 8192;       // 256*512 floats = 512 KB
    float* div_acc  = evt_part + NEVT * DD;              // 8192 floats
    float* evt_acc  = div_acc + BB * DD;                 // 8192 floats

    hipLaunchKernelGGL(kernel_a, dim3(NROLE + NEVT), dim3(256), 0, stream,
                       logits, arg_emb, WRT, WTT, evt_emb, evt_type, part, evt_part);
    hipLaunchKernelGGL(kernel_reduce, dim3(136), dim3(256), 0, stream,
                       part, evt_part, div_acc, evt_acc);
    hipLaunchKernelGGL(kernel_mlp, dim3(BB), dim3(256), 0, stream,
                       div_acc, evt_acc, w1, b1, w2, b2, out);
}